// Round 8
// baseline (284.278 us; speedup 1.0000x reference)
//
#include <hip/hip_runtime.h>

#define F_IN  512
#define F_OUT 128
#define FBIN  32            // nodes per fine bin
#define EPB   8192          // edges per fill partition block (512 thr x 16)
#define C2MAX 1600          // max fine bins (N <= 51200)
#define CAPF  2048          // slab capacity per bin (mean ~1024, ~32 sigma headroom)
#define CPAD  16            // cursor padding: 1 counter per 64B line

typedef __attribute__((ext_vector_type(8))) short  short8;
typedef __attribute__((ext_vector_type(4))) float  floatx4;

__device__ __forceinline__ unsigned short f2bf(float f) {
    unsigned u = __float_as_uint(f);
    return (unsigned short)((u + 0x7FFF + ((u >> 16) & 1)) >> 16);  // RNE
}
__device__ __forceinline__ float bf2f(unsigned b) {
    return __uint_as_float(b << 16);
}

// ---------------------------------------------------------------------------
// prep: blocks 0..127 transpose-convert w fp32 [512][128] -> wt bf16 [128][512];
// blocks 128.. zero the line-padded per-bin cursors (C2*CPAD ints).
// ---------------------------------------------------------------------------
__global__ __launch_bounds__(256) void prep(
    const float* __restrict__ w, unsigned short* __restrict__ wt,
    int* __restrict__ cursor, int C2)
{
    const int tid = threadIdx.x;
    if ((int)blockIdx.x < 128) {
        int g0 = blockIdx.x * 512 + tid;
        #pragma unroll
        for (int r = 0; r < 2; ++r) {
            int gid = g0 + r * 256;
            int n = gid >> 9, k = gid & 511;
            wt[gid] = f2bf(w[(size_t)k * F_OUT + n]);
        }
    } else {
        int c = ((int)blockIdx.x - 128) * 256 + tid;
        if (c < C2 * CPAD) cursor[c] = 0;
    }
}

// ---------------------------------------------------------------------------
// fill_gemm, ROUND-8: fill half replaced by DIRECT per-edge slab append.
// The r1-r7 rank-and-claim machinery (per-block 1563-int LDS zero + 8192 LDS
// hist atomics [the constant 250K SQ_LDS_BANK_CONFLICT cycles] + ~1550
// contended global cursor claims + 16-deep register caches) is deleted.
// Per edge: memory-side atomicAdd on a line-padded cursor returns a unique
// slab slot; 8B scattered store. Slab order is irrelevant (fine_agg re-sorts
// in LDS). Byte-granular L2 dirty merging makes interleaved-line writes safe
// (same mechanism the 5-entry partial-line runs already relied on).
// GEMM half: r7 verbatim (128x128 tile, 8 waves 4Mx2N, 16x16x32 MFMA).
// ---------------------------------------------------------------------------
__global__ __launch_bounds__(512, 1) void fill_gemm(
    const int* __restrict__ ei, const float* __restrict__ ew,
    int* __restrict__ cursor, uint2* __restrict__ ent, int E, int C2, int FB,
    const float* __restrict__ x, const unsigned short* __restrict__ wt,
    unsigned short* __restrict__ h, int N)
{
    __shared__ __align__(16) char smem[(128 * 68 + 128 * 68) * 2];  // 34816 B
    const int tid = threadIdx.x;

    if ((int)blockIdx.x < FB) {
        // ----- fill: direct append -----
        const int base = blockIdx.x * EPB;
        #pragma unroll 4
        for (int j = 0; j < EPB / 512; ++j) {
            int e = base + j * 512 + tid;
            if (e < E) {
                int   src = ei[e];
                int   dst = ei[E + e];
                float wv  = ew[e];
                int bin = dst >> 5;                       // 32-node fine bin
                int o = atomicAdd(&cursor[bin * CPAD], 1);
                if (o < CAPF)                              // overflow -> slow path covers
                    ent[(size_t)bin * CAPF + o] = make_uint2(
                        (unsigned)src | ((unsigned)f2bf(wv) << 16),
                        (unsigned)(dst & (FBIN - 1)));
            }
        }
        return;
    }

    // ----- GEMM: 128x128 tile, 8 waves (4M x 2N), r7 verbatim -----
    unsigned short* sa = (unsigned short*)smem;       // [128][68]
    unsigned short* sb = sa + 128 * 68;               // [128][68]

    const int wave = tid >> 6, lane = tid & 63;
    const int wm   = wave >> 1, wn = wave & 1;        // 4M x 2N wave grid
    const int g    = lane >> 4, l16 = lane & 15;
    const int m0   = ((int)blockIdx.x - FB) * 128;

    const int arow = tid >> 2, aq = tid & 3;          // 128 rows x 4 k-quads (A)
    const int brow = tid >> 2, bq = tid & 3;          // 128 rows x 4 k-quads (B)

    floatx4 acc[2][4];
    #pragma unroll
    for (int rt = 0; rt < 2; ++rt)
        #pragma unroll
        for (int nt = 0; nt < 4; ++nt) acc[rt][nt] = (floatx4)(0.f);

    const bool  avalid = (m0 + arow) < N;
    const float* xp = x + (size_t)(m0 + arow) * F_IN + aq * 16;
    const unsigned short* bp = wt + brow * F_IN + bq * 16;

    float4 ax[4];
    uint4  bv[2];
    #pragma unroll
    for (int i = 0; i < 4; ++i) ax[i] = make_float4(0.f, 0.f, 0.f, 0.f);
    if (avalid) {
        #pragma unroll
        for (int i = 0; i < 4; ++i) ax[i] = ((const float4*)xp)[i];
    }
    #pragma unroll
    for (int i = 0; i < 2; ++i) bv[i] = ((const uint4*)bp)[i];

    for (int s = 0; s < 8; ++s) {
        __syncthreads();
        #pragma unroll
        for (int i = 0; i < 4; ++i) {
            ushort4 t;
            t.x = f2bf(ax[i].x); t.y = f2bf(ax[i].y);
            t.z = f2bf(ax[i].z); t.w = f2bf(ax[i].w);
            *(ushort4*)&sa[arow * 68 + aq * 16 + i * 4] = t;
        }
        #pragma unroll
        for (int i = 0; i < 2; ++i) {
            *(uint2*)&sb[brow * 68 + bq * 16 + i * 8]     = make_uint2(bv[i].x, bv[i].y);
            *(uint2*)&sb[brow * 68 + bq * 16 + i * 8 + 4] = make_uint2(bv[i].z, bv[i].w);
        }
        if (s < 7) {
            int k0n = (s + 1) * 64;
            if (avalid) {
                #pragma unroll
                for (int i = 0; i < 4; ++i) ax[i] = ((const float4*)(xp + k0n))[i];
            }
            #pragma unroll
            for (int i = 0; i < 2; ++i) bv[i] = ((const uint4*)(bp + k0n))[i];
        }
        __syncthreads();

        #pragma unroll
        for (int kc = 0; kc < 2; ++kc) {
            union { ushort4 u[2]; short8 v; } af[2];
            #pragma unroll
            for (int rt = 0; rt < 2; ++rt) {
                int abase = (wm * 32 + rt * 16 + l16) * 68 + kc * 32 + g * 8;
                af[rt].u[0] = *(ushort4*)&sa[abase];
                af[rt].u[1] = *(ushort4*)&sa[abase + 4];
            }
            #pragma unroll
            for (int nt = 0; nt < 4; ++nt) {
                union { ushort4 u[2]; short8 v; } bf;
                int bbase = (wn * 64 + nt * 16 + l16) * 68 + kc * 32 + g * 8;
                bf.u[0] = *(ushort4*)&sb[bbase];
                bf.u[1] = *(ushort4*)&sb[bbase + 4];
                #pragma unroll
                for (int rt = 0; rt < 2; ++rt)
                    acc[rt][nt] = __builtin_amdgcn_mfma_f32_16x16x32_bf16(
                        af[rt].v, bf.v, acc[rt][nt], 0, 0, 0);
            }
        }
    }

    #pragma unroll
    for (int rt = 0; rt < 2; ++rt) {
        #pragma unroll
        for (int nt = 0; nt < 4; ++nt) {
            #pragma unroll
            for (int r = 0; r < 4; ++r) {
                int row = m0 + wm * 32 + rt * 16 + g * 4 + r;
                int col = wn * 64 + nt * 16 + l16;
                if (row < N) h[(size_t)row * F_OUT + col] = f2bf(acc[rt][nt][r]);
            }
        }
    }
}

// ---------------------------------------------------------------------------
// fine_agg (r7 body; only cursor read index changes to the padded layout).
// One block per 32-node fine bin. Two slab passes (hist+scan, node-sorted
// placement into LDS); wave per 8 nodes; slot = lane>>4, q = lane&15 (uint4
// gather); shfl_xor(16)+shfl_xor(32) reduce; fused bias+relu writeout.
// ---------------------------------------------------------------------------
__global__ __launch_bounds__(256) void fine_agg(
    const unsigned short* __restrict__ h, const uint2* __restrict__ ent,
    const int* __restrict__ cursor, const float* __restrict__ bias,
    float* __restrict__ out, int N, int E,
    const int* __restrict__ ei, const float* __restrict__ ew)
{
    __shared__ unsigned ssort[CAPF];          // 8 KB
    __shared__ int lh[FBIN], lcur[FBIN];
    __shared__ int sso[FBIN + 1];

    const int b    = blockIdx.x;
    const int tid  = threadIdx.x;
    const int wave = tid >> 6;
    const int lane = tid & 63;
    const int slot = lane >> 4;               // edge slot 0..3
    const int q    = lane & 15;               // feats q*8 .. q*8+7
    const float4 bv0 = *(const float4*)&bias[q * 8];
    const float4 bv1 = *(const float4*)&bias[q * 8 + 4];
    const int raw  = cursor[b * CPAD];
    const int cnt  = raw < CAPF ? raw : CAPF;
    const uint2* slab = ent + (size_t)b * CAPF;

    if (tid < FBIN) lh[tid] = 0;
    __syncthreads();

    for (int i = tid; i < cnt; i += 256)
        atomicAdd(&lh[(int)slab[i].y], 1);
    __syncthreads();

    if (wave == 0 && lane < FBIN) {
        int v = lh[lane];
        int orig = v;
        #pragma unroll
        for (int off = 1; off < FBIN; off <<= 1) {
            int t = __shfl_up(v, off);
            if (lane >= off) v += t;
        }
        sso[lane]  = v - orig;
        lcur[lane] = v - orig;
        if (lane == FBIN - 1) sso[FBIN] = v;
    }
    __syncthreads();

    if (raw <= CAPF) {
        for (int i = tid; i < cnt; i += 256) {
            uint2 e = slab[i];
            int r = atomicAdd(&lcur[(int)e.y], 1);
            ssort[r] = e.x;
        }
        __syncthreads();

        #pragma unroll 1
        for (int t = 0; t < 8; ++t) {
            int nd   = wave * 8 + t;
            int node = b * FBIN + nd;
            int s = sso[nd], e2 = sso[nd + 1];
            float4 a0 = make_float4(0.f, 0.f, 0.f, 0.f);
            float4 a1 = make_float4(0.f, 0.f, 0.f, 0.f);
            for (int i = s; i < e2; i += 16) {
                #pragma unroll
                for (int j = 0; j < 4; ++j) {
                    int idx = i + j * 4 + slot;
                    unsigned bk = 0;
                    if (idx < e2) bk = ssort[idx];
                    float wgt = bf2f(bk >> 16);
                    uint4 hv = *(const uint4*)&h[(size_t)(bk & 0xFFFF) * F_OUT + q * 8];
                    a0.x += bf2f(hv.x & 0xFFFF) * wgt;
                    a0.y += bf2f(hv.x >> 16)    * wgt;
                    a0.z += bf2f(hv.y & 0xFFFF) * wgt;
                    a0.w += bf2f(hv.y >> 16)    * wgt;
                    a1.x += bf2f(hv.z & 0xFFFF) * wgt;
                    a1.y += bf2f(hv.z >> 16)    * wgt;
                    a1.z += bf2f(hv.w & 0xFFFF) * wgt;
                    a1.w += bf2f(hv.w >> 16)    * wgt;
                }
            }
            a0.x += __shfl_xor(a0.x, 16);
            a0.y += __shfl_xor(a0.y, 16);
            a0.z += __shfl_xor(a0.z, 16);
            a0.w += __shfl_xor(a0.w, 16);
            a1.x += __shfl_xor(a1.x, 16);
            a1.y += __shfl_xor(a1.y, 16);
            a1.z += __shfl_xor(a1.z, 16);
            a1.w += __shfl_xor(a1.w, 16);
            a0.x += __shfl_xor(a0.x, 32);
            a0.y += __shfl_xor(a0.y, 32);
            a0.z += __shfl_xor(a0.z, 32);
            a0.w += __shfl_xor(a0.w, 32);
            a1.x += __shfl_xor(a1.x, 32);
            a1.y += __shfl_xor(a1.y, 32);
            a1.z += __shfl_xor(a1.z, 32);
            a1.w += __shfl_xor(a1.w, 32);
            if (slot == 0 && node < N) {
                float4 o0, o1;
                o0.x = fmaxf(a0.x + bv0.x, 0.f);
                o0.y = fmaxf(a0.y + bv0.y, 0.f);
                o0.z = fmaxf(a0.z + bv0.z, 0.f);
                o0.w = fmaxf(a0.w + bv0.w, 0.f);
                o1.x = fmaxf(a1.x + bv1.x, 0.f);
                o1.y = fmaxf(a1.y + bv1.y, 0.f);
                o1.z = fmaxf(a1.z + bv1.z, 0.f);
                o1.w = fmaxf(a1.w + bv1.w, 0.f);
                *(float4*)&out[(size_t)node * F_OUT + q * 8]     = o0;
                *(float4*)&out[(size_t)node * F_OUT + q * 8 + 4] = o1;
            }
        }
    } else {
        // slab overflow (never expected at this E/N): correct-but-slow path
        // over the raw edge list.
        #pragma unroll 1
        for (int t = 0; t < 8; ++t) {
            int nd   = wave * 8 + t;
            int node = b * FBIN + nd;
            float4 a0 = make_float4(0.f, 0.f, 0.f, 0.f);
            float4 a1 = make_float4(0.f, 0.f, 0.f, 0.f);
            for (int e = slot; e < E; e += 4) {
                if (ei[E + e] == node) {
                    float wgt = ew[e];
                    uint4 hv = *(const uint4*)&h[(size_t)ei[e] * F_OUT + q * 8];
                    a0.x += bf2f(hv.x & 0xFFFF) * wgt;
                    a0.y += bf2f(hv.x >> 16)    * wgt;
                    a0.z += bf2f(hv.y & 0xFFFF) * wgt;
                    a0.w += bf2f(hv.y >> 16)    * wgt;
                    a1.x += bf2f(hv.z & 0xFFFF) * wgt;
                    a1.y += bf2f(hv.z >> 16)    * wgt;
                    a1.z += bf2f(hv.w & 0xFFFF) * wgt;
                    a1.w += bf2f(hv.w >> 16)    * wgt;
                }
            }
            a0.x += __shfl_xor(a0.x, 16);
            a0.y += __shfl_xor(a0.y, 16);
            a0.z += __shfl_xor(a0.z, 16);
            a0.w += __shfl_xor(a0.w, 16);
            a1.x += __shfl_xor(a1.x, 16);
            a1.y += __shfl_xor(a1.y, 16);
            a1.z += __shfl_xor(a1.z, 16);
            a1.w += __shfl_xor(a1.w, 16);
            a0.x += __shfl_xor(a0.x, 32);
            a0.y += __shfl_xor(a0.y, 32);
            a0.z += __shfl_xor(a0.z, 32);
            a0.w += __shfl_xor(a0.w, 32);
            a1.x += __shfl_xor(a1.x, 32);
            a1.y += __shfl_xor(a1.y, 32);
            a1.z += __shfl_xor(a1.z, 32);
            a1.w += __shfl_xor(a1.w, 32);
            if (slot == 0 && node < N) {
                float4 o0, o1;
                o0.x = fmaxf(a0.x + bv0.x, 0.f);
                o0.y = fmaxf(a0.y + bv0.y, 0.f);
                o0.z = fmaxf(a0.z + bv0.z, 0.f);
                o0.w = fmaxf(a0.w + bv0.w, 0.f);
                o1.x = fmaxf(a1.x + bv1.x, 0.f);
                o1.y = fmaxf(a1.y + bv1.y, 0.f);
                o1.z = fmaxf(a1.z + bv1.z, 0.f);
                o1.w = fmaxf(a1.w + bv1.w, 0.f);
                *(float4*)&out[(size_t)node * F_OUT + q * 8]     = o0;
                *(float4*)&out[(size_t)node * F_OUT + q * 8 + 4] = o1;
            }
        }
    }
}

static inline size_t align256(size_t x) { return (x + 255) & ~(size_t)255; }

extern "C" void kernel_launch(void* const* d_in, const int* in_sizes, int n_in,
                              void* d_out, int out_size, void* d_ws, size_t ws_size,
                              hipStream_t stream)
{
    const float* x    = (const float*)d_in[0];   // [N, 512]
    const int*   ei   = (const int*)  d_in[1];   // [2, E] int32
    const float* ew   = (const float*)d_in[2];   // [E]
    const float* w    = (const float*)d_in[3];   // [512, 128]
    const float* bias = (const float*)d_in[4];   // [128]
    float*       out  = (float*)d_out;           // [N, 128]

    const int N  = in_sizes[0] / F_IN;           // 50000
    const int E  = in_sizes[2];                  // 1600000
    const int C2 = (N + FBIN - 1) / FBIN;        // 1563 fine bins

    // workspace layout (~38.7 MB)
    char*  ws = (char*)d_ws;
    size_t off = 0;
    unsigned short* h      = (unsigned short*)(ws + off); off += align256((size_t)N * F_OUT * 2);
    unsigned short* wt     = (unsigned short*)(ws + off); off += align256((size_t)F_OUT * F_IN * 2);
    int*            cursor = (int*)(ws + off);            off += align256((size_t)C2 * CPAD * 4);
    uint2*          ent    = (uint2*)(ws + off);          off += align256((size_t)C2 * CAPF * 8);

    const int FB = (E + EPB - 1) / EPB;          // 196 fill blocks
    const int GB = (N + 127) / 128;              // 391 gemm blocks
    const int ZB = (C2 * CPAD + 255) / 256;      // 98 cursor-zero blocks

    prep<<<128 + ZB, 256, 0, stream>>>(w, wt, cursor, C2);
    fill_gemm<<<FB + GB, 512, 0, stream>>>(ei, ew, cursor, ent, E, C2, FB,
                                           x, wt, h, N);
    fine_agg<<<C2, 256, 0, stream>>>(h, ent, cursor, bias, out, N, E, ei, ew);
}

// Round 9
// 256.039 us; speedup vs baseline: 1.1103x; 1.1103x over previous
//
#include <hip/hip_runtime.h>

#define F_IN  512
#define F_OUT 128
#define FBIN  32            // nodes per fine bin
#define EPB   8192          // edges per fill partition block (512 thr x 16)
#define C2MAX 1600          // max fine bins (N <= 51200)
#define CAPF  2048          // slab capacity per bin (mean ~1024, ~32 sigma headroom)

typedef __attribute__((ext_vector_type(8))) short  short8;
typedef __attribute__((ext_vector_type(4))) float  floatx4;

__device__ __forceinline__ unsigned short f2bf(float f) {
    unsigned u = __float_as_uint(f);
    return (unsigned short)((u + 0x7FFF + ((u >> 16) & 1)) >> 16);  // RNE
}
__device__ __forceinline__ float bf2f(unsigned b) {
    return __uint_as_float(b << 16);
}

// ---------------------------------------------------------------------------
// prep: blocks 0..127 transpose-convert w fp32 [512][128] -> wt bf16 [128][512];
// blocks 128.. zero the per-bin cursors.
// ---------------------------------------------------------------------------
__global__ __launch_bounds__(256) void prep(
    const float* __restrict__ w, unsigned short* __restrict__ wt,
    int* __restrict__ cursor, int C2)
{
    const int tid = threadIdx.x;
    if ((int)blockIdx.x < 128) {
        int g0 = blockIdx.x * 512 + tid;
        #pragma unroll
        for (int r = 0; r < 2; ++r) {
            int gid = g0 + r * 256;
            int n = gid >> 9, k = gid & 511;
            wt[gid] = f2bf(w[(size_t)k * F_OUT + n]);
        }
    } else {
        int c = ((int)blockIdx.x - 128) * 256 + tid;
        if (c < C2) cursor[c] = 0;
    }
}

// ---------------------------------------------------------------------------
// fill (ROUND-9: standalone dispatch, r7 ranked body verbatim).
// LDS rank + one batched cursor claim per bin -> contiguous slab runs.
// Split from the GEMM so rocprof finally attributes the 73 us blend.
// ---------------------------------------------------------------------------
__global__ __launch_bounds__(512) void fill(
    const int* __restrict__ ei, const float* __restrict__ ew,
    int* __restrict__ cursor, uint2* __restrict__ ent, int E, int C2)
{
    __shared__ int lh[C2MAX];
    __shared__ int lbase[C2MAX];
    const int tid = threadIdx.x;

    for (int c = tid; c < C2; c += 512) lh[c] = 0;
    __syncthreads();

    const int base = blockIdx.x * EPB;
    unsigned       mykey[EPB / 512];
    unsigned char  mydl[EPB / 512];
    short          mybin[EPB / 512];
    unsigned short myrank[EPB / 512];

    #pragma unroll
    for (int j = 0; j < EPB / 512; ++j) {
        int e = base + j * 512 + tid;
        mybin[j] = -1;
        if (e < E) {
            int   src = ei[e];
            int   dst = ei[E + e];
            float w   = ew[e];
            int bin = dst >> 5;                       // 32-node fine bin
            mykey[j]  = (unsigned)src | ((unsigned)f2bf(w) << 16);
            mydl[j]   = (unsigned char)(dst & (FBIN - 1));
            mybin[j]  = (short)bin;
            myrank[j] = (unsigned short)atomicAdd(&lh[bin], 1);
        }
    }
    __syncthreads();
    for (int c = tid; c < C2; c += 512)
        if (lh[c] > 0) lbase[c] = atomicAdd(&cursor[c], lh[c]);
    __syncthreads();
    #pragma unroll
    for (int j = 0; j < EPB / 512; ++j) {
        if (mybin[j] >= 0) {
            int o = lbase[mybin[j]] + myrank[j];
            if (o < CAPF)                              // overflow -> slow path covers
                ent[(size_t)(int)mybin[j] * CAPF + o] = make_uint2(mykey[j], mydl[j]);
        }
    }
}

// ---------------------------------------------------------------------------
// gemm (ROUND-9: standalone dispatch, r7 body verbatim).
// h[N,128](bf16) = bf16(x) @ wt. 128x128 tile, 8 waves (4M x 2N),
// 16x16x32 MFMA, LDS sa[128][68] + sb[128][68] = 34.8 KB.
// ---------------------------------------------------------------------------
__global__ __launch_bounds__(512, 1) void gemm(
    const float* __restrict__ x, const unsigned short* __restrict__ wt,
    unsigned short* __restrict__ h, int N)
{
    __shared__ __align__(16) unsigned short sa[128 * 68];
    __shared__ __align__(16) unsigned short sb[128 * 68];
    const int tid = threadIdx.x;

    const int wave = tid >> 6, lane = tid & 63;
    const int wm   = wave >> 1, wn = wave & 1;        // 4M x 2N wave grid
    const int g    = lane >> 4, l16 = lane & 15;
    const int m0   = (int)blockIdx.x * 128;

    const int arow = tid >> 2, aq = tid & 3;          // 128 rows x 4 k-quads (A)
    const int brow = tid >> 2, bq = tid & 3;          // 128 rows x 4 k-quads (B)

    floatx4 acc[2][4];
    #pragma unroll
    for (int rt = 0; rt < 2; ++rt)
        #pragma unroll
        for (int nt = 0; nt < 4; ++nt) acc[rt][nt] = (floatx4)(0.f);

    const bool  avalid = (m0 + arow) < N;
    const float* xp = x + (size_t)(m0 + arow) * F_IN + aq * 16;
    const unsigned short* bp = wt + brow * F_IN + bq * 16;

    float4 ax[4];
    uint4  bv[2];
    #pragma unroll
    for (int i = 0; i < 4; ++i) ax[i] = make_float4(0.f, 0.f, 0.f, 0.f);
    if (avalid) {
        #pragma unroll
        for (int i = 0; i < 4; ++i) ax[i] = ((const float4*)xp)[i];
    }
    #pragma unroll
    for (int i = 0; i < 2; ++i) bv[i] = ((const uint4*)bp)[i];

    for (int s = 0; s < 8; ++s) {
        __syncthreads();
        #pragma unroll
        for (int i = 0; i < 4; ++i) {
            ushort4 t;
            t.x = f2bf(ax[i].x); t.y = f2bf(ax[i].y);
            t.z = f2bf(ax[i].z); t.w = f2bf(ax[i].w);
            *(ushort4*)&sa[arow * 68 + aq * 16 + i * 4] = t;
        }
        #pragma unroll
        for (int i = 0; i < 2; ++i) {
            *(uint2*)&sb[brow * 68 + bq * 16 + i * 8]     = make_uint2(bv[i].x, bv[i].y);
            *(uint2*)&sb[brow * 68 + bq * 16 + i * 8 + 4] = make_uint2(bv[i].z, bv[i].w);
        }
        if (s < 7) {
            int k0n = (s + 1) * 64;
            if (avalid) {
                #pragma unroll
                for (int i = 0; i < 4; ++i) ax[i] = ((const float4*)(xp + k0n))[i];
            }
            #pragma unroll
            for (int i = 0; i < 2; ++i) bv[i] = ((const uint4*)(bp + k0n))[i];
        }
        __syncthreads();

        #pragma unroll
        for (int kc = 0; kc < 2; ++kc) {
            union { ushort4 u[2]; short8 v; } af[2];
            #pragma unroll
            for (int rt = 0; rt < 2; ++rt) {
                int abase = (wm * 32 + rt * 16 + l16) * 68 + kc * 32 + g * 8;
                af[rt].u[0] = *(ushort4*)&sa[abase];
                af[rt].u[1] = *(ushort4*)&sa[abase + 4];
            }
            #pragma unroll
            for (int nt = 0; nt < 4; ++nt) {
                union { ushort4 u[2]; short8 v; } bf;
                int bbase = (wn * 64 + nt * 16 + l16) * 68 + kc * 32 + g * 8;
                bf.u[0] = *(ushort4*)&sb[bbase];
                bf.u[1] = *(ushort4*)&sb[bbase + 4];
                #pragma unroll
                for (int rt = 0; rt < 2; ++rt)
                    acc[rt][nt] = __builtin_amdgcn_mfma_f32_16x16x32_bf16(
                        af[rt].v, bf.v, acc[rt][nt], 0, 0, 0);
            }
        }
    }

    #pragma unroll
    for (int rt = 0; rt < 2; ++rt) {
        #pragma unroll
        for (int nt = 0; nt < 4; ++nt) {
            #pragma unroll
            for (int r = 0; r < 4; ++r) {
                int row = m0 + wm * 32 + rt * 16 + g * 4 + r;
                int col = wn * 64 + nt * 16 + l16;
                if (row < N) h[(size_t)row * F_OUT + col] = f2bf(acc[rt][nt][r]);
            }
        }
    }
}

// ---------------------------------------------------------------------------
// fine_agg (r7 body, unpadded cursor): one block per 32-node fine bin.
// Two slab passes (hist+scan, node-sorted placement into LDS); wave per 8
// nodes; slot = lane>>4, q = lane&15 (uint4 gather); shfl_xor(16)+(32)
// reduce; fused bias+relu 2x float4 writeout.
// ---------------------------------------------------------------------------
__global__ __launch_bounds__(256) void fine_agg(
    const unsigned short* __restrict__ h, const uint2* __restrict__ ent,
    const int* __restrict__ cursor, const float* __restrict__ bias,
    float* __restrict__ out, int N, int E,
    const int* __restrict__ ei, const float* __restrict__ ew)
{
    __shared__ unsigned ssort[CAPF];          // 8 KB
    __shared__ int lh[FBIN], lcur[FBIN];
    __shared__ int sso[FBIN + 1];

    const int b    = blockIdx.x;
    const int tid  = threadIdx.x;
    const int wave = tid >> 6;
    const int lane = tid & 63;
    const int slot = lane >> 4;               // edge slot 0..3
    const int q    = lane & 15;               // feats q*8 .. q*8+7
    const float4 bv0 = *(const float4*)&bias[q * 8];
    const float4 bv1 = *(const float4*)&bias[q * 8 + 4];
    const int raw  = cursor[b];
    const int cnt  = raw < CAPF ? raw : CAPF;
    const uint2* slab = ent + (size_t)b * CAPF;

    if (tid < FBIN) lh[tid] = 0;
    __syncthreads();

    for (int i = tid; i < cnt; i += 256)
        atomicAdd(&lh[(int)slab[i].y], 1);
    __syncthreads();

    if (wave == 0 && lane < FBIN) {
        int v = lh[lane];
        int orig = v;
        #pragma unroll
        for (int off = 1; off < FBIN; off <<= 1) {
            int t = __shfl_up(v, off);
            if (lane >= off) v += t;
        }
        sso[lane]  = v - orig;
        lcur[lane] = v - orig;
        if (lane == FBIN - 1) sso[FBIN] = v;
    }
    __syncthreads();

    if (raw <= CAPF) {
        for (int i = tid; i < cnt; i += 256) {
            uint2 e = slab[i];
            int r = atomicAdd(&lcur[(int)e.y], 1);
            ssort[r] = e.x;
        }
        __syncthreads();

        #pragma unroll 1
        for (int t = 0; t < 8; ++t) {
            int nd   = wave * 8 + t;
            int node = b * FBIN + nd;
            int s = sso[nd], e2 = sso[nd + 1];
            float4 a0 = make_float4(0.f, 0.f, 0.f, 0.f);
            float4 a1 = make_float4(0.f, 0.f, 0.f, 0.f);
            for (int i = s; i < e2; i += 16) {
                #pragma unroll
                for (int j = 0; j < 4; ++j) {
                    int idx = i + j * 4 + slot;
                    unsigned bk = 0;
                    if (idx < e2) bk = ssort[idx];
                    float wgt = bf2f(bk >> 16);
                    uint4 hv = *(const uint4*)&h[(size_t)(bk & 0xFFFF) * F_OUT + q * 8];
                    a0.x += bf2f(hv.x & 0xFFFF) * wgt;
                    a0.y += bf2f(hv.x >> 16)    * wgt;
                    a0.z += bf2f(hv.y & 0xFFFF) * wgt;
                    a0.w += bf2f(hv.y >> 16)    * wgt;
                    a1.x += bf2f(hv.z & 0xFFFF) * wgt;
                    a1.y += bf2f(hv.z >> 16)    * wgt;
                    a1.z += bf2f(hv.w & 0xFFFF) * wgt;
                    a1.w += bf2f(hv.w >> 16)    * wgt;
                }
            }
            a0.x += __shfl_xor(a0.x, 16);
            a0.y += __shfl_xor(a0.y, 16);
            a0.z += __shfl_xor(a0.z, 16);
            a0.w += __shfl_xor(a0.w, 16);
            a1.x += __shfl_xor(a1.x, 16);
            a1.y += __shfl_xor(a1.y, 16);
            a1.z += __shfl_xor(a1.z, 16);
            a1.w += __shfl_xor(a1.w, 16);
            a0.x += __shfl_xor(a0.x, 32);
            a0.y += __shfl_xor(a0.y, 32);
            a0.z += __shfl_xor(a0.z, 32);
            a0.w += __shfl_xor(a0.w, 32);
            a1.x += __shfl_xor(a1.x, 32);
            a1.y += __shfl_xor(a1.y, 32);
            a1.z += __shfl_xor(a1.z, 32);
            a1.w += __shfl_xor(a1.w, 32);
            if (slot == 0 && node < N) {
                float4 o0, o1;
                o0.x = fmaxf(a0.x + bv0.x, 0.f);
                o0.y = fmaxf(a0.y + bv0.y, 0.f);
                o0.z = fmaxf(a0.z + bv0.z, 0.f);
                o0.w = fmaxf(a0.w + bv0.w, 0.f);
                o1.x = fmaxf(a1.x + bv1.x, 0.f);
                o1.y = fmaxf(a1.y + bv1.y, 0.f);
                o1.z = fmaxf(a1.z + bv1.z, 0.f);
                o1.w = fmaxf(a1.w + bv1.w, 0.f);
                *(float4*)&out[(size_t)node * F_OUT + q * 8]     = o0;
                *(float4*)&out[(size_t)node * F_OUT + q * 8 + 4] = o1;
            }
        }
    } else {
        // slab overflow (never expected at this E/N): correct-but-slow path
        // over the raw edge list.
        #pragma unroll 1
        for (int t = 0; t < 8; ++t) {
            int nd   = wave * 8 + t;
            int node = b * FBIN + nd;
            float4 a0 = make_float4(0.f, 0.f, 0.f, 0.f);
            float4 a1 = make_float4(0.f, 0.f, 0.f, 0.f);
            for (int e = slot; e < E; e += 4) {
                if (ei[E + e] == node) {
                    float wgt = ew[e];
                    uint4 hv = *(const uint4*)&h[(size_t)ei[e] * F_OUT + q * 8];
                    a0.x += bf2f(hv.x & 0xFFFF) * wgt;
                    a0.y += bf2f(hv.x >> 16)    * wgt;
                    a0.z += bf2f(hv.y & 0xFFFF) * wgt;
                    a0.w += bf2f(hv.y >> 16)    * wgt;
                    a1.x += bf2f(hv.z & 0xFFFF) * wgt;
                    a1.y += bf2f(hv.z >> 16)    * wgt;
                    a1.z += bf2f(hv.w & 0xFFFF) * wgt;
                    a1.w += bf2f(hv.w >> 16)    * wgt;
                }
            }
            a0.x += __shfl_xor(a0.x, 16);
            a0.y += __shfl_xor(a0.y, 16);
            a0.z += __shfl_xor(a0.z, 16);
            a0.w += __shfl_xor(a0.w, 16);
            a1.x += __shfl_xor(a1.x, 16);
            a1.y += __shfl_xor(a1.y, 16);
            a1.z += __shfl_xor(a1.z, 16);
            a1.w += __shfl_xor(a1.w, 16);
            a0.x += __shfl_xor(a0.x, 32);
            a0.y += __shfl_xor(a0.y, 32);
            a0.z += __shfl_xor(a0.z, 32);
            a0.w += __shfl_xor(a0.w, 32);
            a1.x += __shfl_xor(a1.x, 32);
            a1.y += __shfl_xor(a1.y, 32);
            a1.z += __shfl_xor(a1.z, 32);
            a1.w += __shfl_xor(a1.w, 32);
            if (slot == 0 && node < N) {
                float4 o0, o1;
                o0.x = fmaxf(a0.x + bv0.x, 0.f);
                o0.y = fmaxf(a0.y + bv0.y, 0.f);
                o0.z = fmaxf(a0.z + bv0.z, 0.f);
                o0.w = fmaxf(a0.w + bv0.w, 0.f);
                o1.x = fmaxf(a1.x + bv1.x, 0.f);
                o1.y = fmaxf(a1.y + bv1.y, 0.f);
                o1.z = fmaxf(a1.z + bv1.z, 0.f);
                o1.w = fmaxf(a1.w + bv1.w, 0.f);
                *(float4*)&out[(size_t)node * F_OUT + q * 8]     = o0;
                *(float4*)&out[(size_t)node * F_OUT + q * 8 + 4] = o1;
            }
        }
    }
}

static inline size_t align256(size_t x) { return (x + 255) & ~(size_t)255; }

extern "C" void kernel_launch(void* const* d_in, const int* in_sizes, int n_in,
                              void* d_out, int out_size, void* d_ws, size_t ws_size,
                              hipStream_t stream)
{
    const float* x    = (const float*)d_in[0];   // [N, 512]
    const int*   ei   = (const int*)  d_in[1];   // [2, E] int32
    const float* ew   = (const float*)d_in[2];   // [E]
    const float* w    = (const float*)d_in[3];   // [512, 128]
    const float* bias = (const float*)d_in[4];   // [128]
    float*       out  = (float*)d_out;           // [N, 128]

    const int N  = in_sizes[0] / F_IN;           // 50000
    const int E  = in_sizes[2];                  // 1600000
    const int C2 = (N + FBIN - 1) / FBIN;        // 1563 fine bins

    // workspace layout (~38.6 MB)
    char*  ws = (char*)d_ws;
    size_t off = 0;
    unsigned short* h      = (unsigned short*)(ws + off); off += align256((size_t)N * F_OUT * 2);
    unsigned short* wt     = (unsigned short*)(ws + off); off += align256((size_t)F_OUT * F_IN * 2);
    int*            cursor = (int*)(ws + off);            off += align256((size_t)C2 * 4);
    uint2*          ent    = (uint2*)(ws + off);          off += align256((size_t)C2 * CAPF * 8);

    const int FB = (E + EPB - 1) / EPB;          // 196 fill blocks
    const int GB = (N + 127) / 128;              // 391 gemm blocks
    const int ZB = (C2 + 255) / 256;             // 7 cursor-zero blocks

    prep<<<128 + ZB, 256, 0, stream>>>(w, wt, cursor, C2);
    fill<<<FB, 512, 0, stream>>>(ei, ew, cursor, ent, E, C2);
    gemm<<<GB, 512, 0, stream>>>(x, wt, h, N);
    fine_agg<<<C2, 256, 0, stream>>>(h, ent, cursor, bias, out, N, E, ei, ew);
}

// Round 10
// 254.435 us; speedup vs baseline: 1.1173x; 1.0063x over previous
//
#include <hip/hip_runtime.h>

#define F_IN  512
#define F_OUT 128
#define FBIN  32            // nodes per fine bin
#define EPB   8192          // edges per fill partition block (512 thr x 16)
#define C2MAX 1600          // max fine bins (N <= 51200)
#define CAPF  2048          // slab capacity per bin (mean ~1024, ~32 sigma headroom)

typedef __attribute__((ext_vector_type(8))) short  short8;
typedef __attribute__((ext_vector_type(4))) float  floatx4;

__device__ __forceinline__ unsigned short f2bf(float f) {
    unsigned u = __float_as_uint(f);
    return (unsigned short)((u + 0x7FFF + ((u >> 16) & 1)) >> 16);  // RNE
}
__device__ __forceinline__ float bf2f(unsigned b) {
    return __uint_as_float(b << 16);
}

// ---------------------------------------------------------------------------
// prep: blocks 0..127 transpose-convert w fp32 [512][128] -> wt bf16 [128][512];
// blocks 128.. zero the per-bin cursors.
// ---------------------------------------------------------------------------
__global__ __launch_bounds__(256) void prep(
    const float* __restrict__ w, unsigned short* __restrict__ wt,
    int* __restrict__ cursor, int C2)
{
    const int tid = threadIdx.x;
    if ((int)blockIdx.x < 128) {
        int g0 = blockIdx.x * 512 + tid;
        #pragma unroll
        for (int r = 0; r < 2; ++r) {
            int gid = g0 + r * 256;
            int n = gid >> 9, k = gid & 511;
            wt[gid] = f2bf(w[(size_t)k * F_OUT + n]);
        }
    } else {
        int c = ((int)blockIdx.x - 128) * 256 + tid;
        if (c < C2) cursor[c] = 0;
    }
}

// ---------------------------------------------------------------------------
// fill (r9 body verbatim): LDS rank + one batched cursor claim per bin ->
// contiguous slab runs.
// ---------------------------------------------------------------------------
__global__ __launch_bounds__(512) void fill(
    const int* __restrict__ ei, const float* __restrict__ ew,
    int* __restrict__ cursor, uint2* __restrict__ ent, int E, int C2)
{
    __shared__ int lh[C2MAX];
    __shared__ int lbase[C2MAX];
    const int tid = threadIdx.x;

    for (int c = tid; c < C2; c += 512) lh[c] = 0;
    __syncthreads();

    const int base = blockIdx.x * EPB;
    unsigned       mykey[EPB / 512];
    unsigned char  mydl[EPB / 512];
    short          mybin[EPB / 512];
    unsigned short myrank[EPB / 512];

    #pragma unroll
    for (int j = 0; j < EPB / 512; ++j) {
        int e = base + j * 512 + tid;
        mybin[j] = -1;
        if (e < E) {
            int   src = ei[e];
            int   dst = ei[E + e];
            float w   = ew[e];
            int bin = dst >> 5;                       // 32-node fine bin
            mykey[j]  = (unsigned)src | ((unsigned)f2bf(w) << 16);
            mydl[j]   = (unsigned char)(dst & (FBIN - 1));
            mybin[j]  = (short)bin;
            myrank[j] = (unsigned short)atomicAdd(&lh[bin], 1);
        }
    }
    __syncthreads();
    for (int c = tid; c < C2; c += 512)
        if (lh[c] > 0) lbase[c] = atomicAdd(&cursor[c], lh[c]);
    __syncthreads();
    #pragma unroll
    for (int j = 0; j < EPB / 512; ++j) {
        if (mybin[j] >= 0) {
            int o = lbase[mybin[j]] + myrank[j];
            if (o < CAPF)                              // overflow -> slow path covers
                ent[(size_t)(int)mybin[j] * CAPF + o] = make_uint2(mykey[j], mydl[j]);
        }
    }
}

// ---------------------------------------------------------------------------
// gemm, ROUND-10: h[N,128](bf16) = bf16(x) @ wt. 128x128 tile, 8 waves
// (4M x 2N), 16x16x32 MFMA. SINGLE CHANGE vs r9: stage-loop reorder.
// Old: B1 -> writeLDS(s) -> issue loads(s+1) -> B2 [vmcnt(0) DRAINS the
// fresh loads with zero covering work] -> MFMA(s).  Full HBM latency
// exposed per stage; MFMA ran with nothing in flight.
// New: writeLDS(0); per stage: B1 -> issue loads(s+1) -> MFMA(s) [loads
// in flight under compute] -> B2 [drain lands post-MFMA] -> writeLDS(s+1).
// Same barrier count, same single LDS buffer (writes of s+1 only after B2
// confirms all reads of s).
// ---------------------------------------------------------------------------
__global__ __launch_bounds__(512, 1) void gemm(
    const float* __restrict__ x, const unsigned short* __restrict__ wt,
    unsigned short* __restrict__ h, int N)
{
    __shared__ __align__(16) unsigned short sa[128 * 68];
    __shared__ __align__(16) unsigned short sb[128 * 68];
    const int tid = threadIdx.x;

    const int wave = tid >> 6, lane = tid & 63;
    const int wm   = wave >> 1, wn = wave & 1;        // 4M x 2N wave grid
    const int g    = lane >> 4, l16 = lane & 15;
    const int m0   = (int)blockIdx.x * 128;

    const int arow = tid >> 2, aq = tid & 3;          // 128 rows x 4 k-quads (A)
    const int brow = tid >> 2, bq = tid & 3;          // 128 rows x 4 k-quads (B)

    floatx4 acc[2][4];
    #pragma unroll
    for (int rt = 0; rt < 2; ++rt)
        #pragma unroll
        for (int nt = 0; nt < 4; ++nt) acc[rt][nt] = (floatx4)(0.f);

    const bool  avalid = (m0 + arow) < N;
    const float* xp = x + (size_t)(m0 + arow) * F_IN + aq * 16;
    const unsigned short* bp = wt + brow * F_IN + bq * 16;

    float4 ax[4];
    uint4  bv[2];
    #pragma unroll
    for (int i = 0; i < 4; ++i) ax[i] = make_float4(0.f, 0.f, 0.f, 0.f);
    if (avalid) {
        #pragma unroll
        for (int i = 0; i < 4; ++i) ax[i] = ((const float4*)xp)[i];
    }
    #pragma unroll
    for (int i = 0; i < 2; ++i) bv[i] = ((const uint4*)bp)[i];

    // initial LDS write of stage 0 (before first barrier)
    #pragma unroll
    for (int i = 0; i < 4; ++i) {
        ushort4 t;
        t.x = f2bf(ax[i].x); t.y = f2bf(ax[i].y);
        t.z = f2bf(ax[i].z); t.w = f2bf(ax[i].w);
        *(ushort4*)&sa[arow * 68 + aq * 16 + i * 4] = t;
    }
    #pragma unroll
    for (int i = 0; i < 2; ++i) {
        *(uint2*)&sb[brow * 68 + bq * 16 + i * 8]     = make_uint2(bv[i].x, bv[i].y);
        *(uint2*)&sb[brow * 68 + bq * 16 + i * 8 + 4] = make_uint2(bv[i].z, bv[i].w);
    }

    for (int s = 0; s < 8; ++s) {
        __syncthreads();                 // B1: stage-s LDS writes visible

        if (s < 7) {                     // issue next-stage loads NOW;
            int k0n = (s + 1) * 64;      // they fly under the MFMA phase
            if (avalid) {
                #pragma unroll
                for (int i = 0; i < 4; ++i) ax[i] = ((const float4*)(xp + k0n))[i];
            }
            #pragma unroll
            for (int i = 0; i < 2; ++i) bv[i] = ((const uint4*)(bp + k0n))[i];
        }

        #pragma unroll
        for (int kc = 0; kc < 2; ++kc) {
            union { ushort4 u[2]; short8 v; } af[2];
            #pragma unroll
            for (int rt = 0; rt < 2; ++rt) {
                int abase = (wm * 32 + rt * 16 + l16) * 68 + kc * 32 + g * 8;
                af[rt].u[0] = *(ushort4*)&sa[abase];
                af[rt].u[1] = *(ushort4*)&sa[abase + 4];
            }
            #pragma unroll
            for (int nt = 0; nt < 4; ++nt) {
                union { ushort4 u[2]; short8 v; } bf;
                int bbase = (wn * 64 + nt * 16 + l16) * 68 + kc * 32 + g * 8;
                bf.u[0] = *(ushort4*)&sb[bbase];
                bf.u[1] = *(ushort4*)&sb[bbase + 4];
                #pragma unroll
                for (int rt = 0; rt < 2; ++rt)
                    acc[rt][nt] = __builtin_amdgcn_mfma_f32_16x16x32_bf16(
                        af[rt].v, bf.v, acc[rt][nt], 0, 0, 0);
            }
        }

        __syncthreads();                 // B2: all reads of stage s done;
                                         // vmcnt drain lands AFTER the MFMAs
        if (s < 7) {
            #pragma unroll
            for (int i = 0; i < 4; ++i) {
                ushort4 t;
                t.x = f2bf(ax[i].x); t.y = f2bf(ax[i].y);
                t.z = f2bf(ax[i].z); t.w = f2bf(ax[i].w);
                *(ushort4*)&sa[arow * 68 + aq * 16 + i * 4] = t;
            }
            #pragma unroll
            for (int i = 0; i < 2; ++i) {
                *(uint2*)&sb[brow * 68 + bq * 16 + i * 8]     = make_uint2(bv[i].x, bv[i].y);
                *(uint2*)&sb[brow * 68 + bq * 16 + i * 8 + 4] = make_uint2(bv[i].z, bv[i].w);
            }
        }
    }

    #pragma unroll
    for (int rt = 0; rt < 2; ++rt) {
        #pragma unroll
        for (int nt = 0; nt < 4; ++nt) {
            #pragma unroll
            for (int r = 0; r < 4; ++r) {
                int row = m0 + wm * 32 + rt * 16 + g * 4 + r;
                int col = wn * 64 + nt * 16 + l16;
                if (row < N) h[(size_t)row * F_OUT + col] = f2bf(acc[rt][nt][r]);
            }
        }
    }
}

// ---------------------------------------------------------------------------
// fine_agg (r9 body verbatim): one block per 32-node fine bin. Two slab
// passes (hist+scan, node-sorted placement into LDS); wave per 8 nodes;
// slot = lane>>4, q = lane&15 (uint4 gather); shfl_xor(16)+(32) reduce;
// fused bias+relu 2x float4 writeout.
// ---------------------------------------------------------------------------
__global__ __launch_bounds__(256) void fine_agg(
    const unsigned short* __restrict__ h, const uint2* __restrict__ ent,
    const int* __restrict__ cursor, const float* __restrict__ bias,
    float* __restrict__ out, int N, int E,
    const int* __restrict__ ei, const float* __restrict__ ew)
{
    __shared__ unsigned ssort[CAPF];          // 8 KB
    __shared__ int lh[FBIN], lcur[FBIN];
    __shared__ int sso[FBIN + 1];

    const int b    = blockIdx.x;
    const int tid  = threadIdx.x;
    const int wave = tid >> 6;
    const int lane = tid & 63;
    const int slot = lane >> 4;               // edge slot 0..3
    const int q    = lane & 15;               // feats q*8 .. q*8+7
    const float4 bv0 = *(const float4*)&bias[q * 8];
    const float4 bv1 = *(const float4*)&bias[q * 8 + 4];
    const int raw  = cursor[b];
    const int cnt  = raw < CAPF ? raw : CAPF;
    const uint2* slab = ent + (size_t)b * CAPF;

    if (tid < FBIN) lh[tid] = 0;
    __syncthreads();

    for (int i = tid; i < cnt; i += 256)
        atomicAdd(&lh[(int)slab[i].y], 1);
    __syncthreads();

    if (wave == 0 && lane < FBIN) {
        int v = lh[lane];
        int orig = v;
        #pragma unroll
        for (int off = 1; off < FBIN; off <<= 1) {
            int t = __shfl_up(v, off);
            if (lane >= off) v += t;
        }
        sso[lane]  = v - orig;
        lcur[lane] = v - orig;
        if (lane == FBIN - 1) sso[FBIN] = v;
    }
    __syncthreads();

    if (raw <= CAPF) {
        for (int i = tid; i < cnt; i += 256) {
            uint2 e = slab[i];
            int r = atomicAdd(&lcur[(int)e.y], 1);
            ssort[r] = e.x;
        }
        __syncthreads();

        #pragma unroll 1
        for (int t = 0; t < 8; ++t) {
            int nd   = wave * 8 + t;
            int node = b * FBIN + nd;
            int s = sso[nd], e2 = sso[nd + 1];
            float4 a0 = make_float4(0.f, 0.f, 0.f, 0.f);
            float4 a1 = make_float4(0.f, 0.f, 0.f, 0.f);
            for (int i = s; i < e2; i += 16) {
                #pragma unroll
                for (int j = 0; j < 4; ++j) {
                    int idx = i + j * 4 + slot;
                    unsigned bk = 0;
                    if (idx < e2) bk = ssort[idx];
                    float wgt = bf2f(bk >> 16);
                    uint4 hv = *(const uint4*)&h[(size_t)(bk & 0xFFFF) * F_OUT + q * 8];
                    a0.x += bf2f(hv.x & 0xFFFF) * wgt;
                    a0.y += bf2f(hv.x >> 16)    * wgt;
                    a0.z += bf2f(hv.y & 0xFFFF) * wgt;
                    a0.w += bf2f(hv.y >> 16)    * wgt;
                    a1.x += bf2f(hv.z & 0xFFFF) * wgt;
                    a1.y += bf2f(hv.z >> 16)    * wgt;
                    a1.z += bf2f(hv.w & 0xFFFF) * wgt;
                    a1.w += bf2f(hv.w >> 16)    * wgt;
                }
            }
            a0.x += __shfl_xor(a0.x, 16);
            a0.y += __shfl_xor(a0.y, 16);
            a0.z += __shfl_xor(a0.z, 16);
            a0.w += __shfl_xor(a0.w, 16);
            a1.x += __shfl_xor(a1.x, 16);
            a1.y += __shfl_xor(a1.y, 16);
            a1.z += __shfl_xor(a1.z, 16);
            a1.w += __shfl_xor(a1.w, 16);
            a0.x += __shfl_xor(a0.x, 32);
            a0.y += __shfl_xor(a0.y, 32);
            a0.z += __shfl_xor(a0.z, 32);
            a0.w += __shfl_xor(a0.w, 32);
            a1.x += __shfl_xor(a1.x, 32);
            a1.y += __shfl_xor(a1.y, 32);
            a1.z += __shfl_xor(a1.z, 32);
            a1.w += __shfl_xor(a1.w, 32);
            if (slot == 0 && node < N) {
                float4 o0, o1;
                o0.x = fmaxf(a0.x + bv0.x, 0.f);
                o0.y = fmaxf(a0.y + bv0.y, 0.f);
                o0.z = fmaxf(a0.z + bv0.z, 0.f);
                o0.w = fmaxf(a0.w + bv0.w, 0.f);
                o1.x = fmaxf(a1.x + bv1.x, 0.f);
                o1.y = fmaxf(a1.y + bv1.y, 0.f);
                o1.z = fmaxf(a1.z + bv1.z, 0.f);
                o1.w = fmaxf(a1.w + bv1.w, 0.f);
                *(float4*)&out[(size_t)node * F_OUT + q * 8]     = o0;
                *(float4*)&out[(size_t)node * F_OUT + q * 8 + 4] = o1;
            }
        }
    } else {
        // slab overflow (never expected at this E/N): correct-but-slow path
        // over the raw edge list.
        #pragma unroll 1
        for (int t = 0; t < 8; ++t) {
            int nd   = wave * 8 + t;
            int node = b * FBIN + nd;
            float4 a0 = make_float4(0.f, 0.f, 0.f, 0.f);
            float4 a1 = make_float4(0.f, 0.f, 0.f, 0.f);
            for (int e = slot; e < E; e += 4) {
                if (ei[E + e] == node) {
                    float wgt = ew[e];
                    uint4 hv = *(const uint4*)&h[(size_t)ei[e] * F_OUT + q * 8];
                    a0.x += bf2f(hv.x & 0xFFFF) * wgt;
                    a0.y += bf2f(hv.x >> 16)    * wgt;
                    a0.z += bf2f(hv.y & 0xFFFF) * wgt;
                    a0.w += bf2f(hv.y >> 16)    * wgt;
                    a1.x += bf2f(hv.z & 0xFFFF) * wgt;
                    a1.y += bf2f(hv.z >> 16)    * wgt;
                    a1.z += bf2f(hv.w & 0xFFFF) * wgt;
                    a1.w += bf2f(hv.w >> 16)    * wgt;
                }
            }
            a0.x += __shfl_xor(a0.x, 16);
            a0.y += __shfl_xor(a0.y, 16);
            a0.z += __shfl_xor(a0.z, 16);
            a0.w += __shfl_xor(a0.w, 16);
            a1.x += __shfl_xor(a1.x, 16);
            a1.y += __shfl_xor(a1.y, 16);
            a1.z += __shfl_xor(a1.z, 16);
            a1.w += __shfl_xor(a1.w, 16);
            a0.x += __shfl_xor(a0.x, 32);
            a0.y += __shfl_xor(a0.y, 32);
            a0.z += __shfl_xor(a0.z, 32);
            a0.w += __shfl_xor(a0.w, 32);
            a1.x += __shfl_xor(a1.x, 32);
            a1.y += __shfl_xor(a1.y, 32);
            a1.z += __shfl_xor(a1.z, 32);
            a1.w += __shfl_xor(a1.w, 32);
            if (slot == 0 && node < N) {
                float4 o0, o1;
                o0.x = fmaxf(a0.x + bv0.x, 0.f);
                o0.y = fmaxf(a0.y + bv0.y, 0.f);
                o0.z = fmaxf(a0.z + bv0.z, 0.f);
                o0.w = fmaxf(a0.w + bv0.w, 0.f);
                o1.x = fmaxf(a1.x + bv1.x, 0.f);
                o1.y = fmaxf(a1.y + bv1.y, 0.f);
                o1.z = fmaxf(a1.z + bv1.z, 0.f);
                o1.w = fmaxf(a1.w + bv1.w, 0.f);
                *(float4*)&out[(size_t)node * F_OUT + q * 8]     = o0;
                *(float4*)&out[(size_t)node * F_OUT + q * 8 + 4] = o1;
            }
        }
    }
}

static inline size_t align256(size_t x) { return (x + 255) & ~(size_t)255; }

extern "C" void kernel_launch(void* const* d_in, const int* in_sizes, int n_in,
                              void* d_out, int out_size, void* d_ws, size_t ws_size,
                              hipStream_t stream)
{
    const float* x    = (const float*)d_in[0];   // [N, 512]
    const int*   ei   = (const int*)  d_in[1];   // [2, E] int32
    const float* ew   = (const float*)d_in[2];   // [E]
    const float* w    = (const float*)d_in[3];   // [512, 128]
    const float* bias = (const float*)d_in[4];   // [128]
    float*       out  = (float*)d_out;           // [N, 128]

    const int N  = in_sizes[0] / F_IN;           // 50000
    const int E  = in_sizes[2];                  // 1600000
    const int C2 = (N + FBIN - 1) / FBIN;        // 1563 fine bins

    // workspace layout (~38.6 MB)
    char*  ws = (char*)d_ws;
    size_t off = 0;
    unsigned short* h      = (unsigned short*)(ws + off); off += align256((size_t)N * F_OUT * 2);
    unsigned short* wt     = (unsigned short*)(ws + off); off += align256((size_t)F_OUT * F_IN * 2);
    int*            cursor = (int*)(ws + off);            off += align256((size_t)C2 * 4);
    uint2*          ent    = (uint2*)(ws + off);          off += align256((size_t)C2 * CAPF * 8);

    const int FB = (E + EPB - 1) / EPB;          // 196 fill blocks
    const int GB = (N + 127) / 128;              // 391 gemm blocks
    const int ZB = (C2 + 255) / 256;             // 7 cursor-zero blocks

    prep<<<128 + ZB, 256, 0, stream>>>(w, wt, cursor, C2);
    fill<<<FB, 512, 0, stream>>>(ei, ew, cursor, ent, E, C2);
    gemm<<<GB, 512, 0, stream>>>(x, wt, h, N);
    fine_agg<<<C2, 256, 0, stream>>>(h, ent, cursor, bias, out, N, E, ei, ew);
}